// Round 2
// baseline (521.186 us; speedup 1.0000x reference)
//
#include <hip/hip_runtime.h>

typedef _Float16 f16;
typedef __attribute__((ext_vector_type(8))) _Float16 half8;
typedef __attribute__((ext_vector_type(4))) _Float16 half4;
typedef __attribute__((ext_vector_type(4))) float f32x4;

#define S_LEN 4096
#define HID   768
#define NH    12
#define HD    64

// ---------------- convert hidden_states f32 -> f16 ----------------
__global__ __launch_bounds__(256) void k_convert_x(const float* __restrict__ x,
                                                   f16* __restrict__ xb) {
  int i = blockIdx.x * 256 + threadIdx.x;          // one float4 per thread
  float4 v = ((const float4*)x)[i];
  half4 h;
  h[0] = (f16)v.x; h[1] = (f16)v.y; h[2] = (f16)v.z; h[3] = (f16)v.w;
  *(half4*)&xb[(size_t)i * 4] = h;
}

// ---------------- transpose W [K,N] -> wt [N,K], f32 -> f16 ----------------
__global__ __launch_bounds__(256) void k_transw(const float* __restrict__ Wq,
                                                const float* __restrict__ Wk,
                                                const float* __restrict__ Wv,
                                                f16* __restrict__ wtb) {
  __shared__ float tile[32][33];
  const float* W = (blockIdx.z == 0) ? Wq : (blockIdx.z == 1 ? Wk : Wv);
  f16* wt = wtb + (size_t)blockIdx.z * HID * HID;
  int k0 = blockIdx.y * 32, n0 = blockIdx.x * 32;
  int tx = threadIdx.x, ty = threadIdx.y;
  #pragma unroll
  for (int j = ty; j < 32; j += 8)
    tile[j][tx] = W[(size_t)(k0 + j) * HID + n0 + tx];
  __syncthreads();
  #pragma unroll
  for (int j = ty; j < 32; j += 8)
    wt[(size_t)(n0 + j) * HID + k0 + tx] = (f16)tile[tx][j];
}

// ---------------- QKV projection GEMM (m97-style, 128x128 tile) ----------------
__global__ __launch_bounds__(256) void k_gemm_qkv(const f16* __restrict__ xb,
                                                  const f16* __restrict__ wtb,
                                                  const float* __restrict__ bq,
                                                  const float* __restrict__ bk,
                                                  const float* __restrict__ bv,
                                                  f16* __restrict__ qo,
                                                  f16* __restrict__ ko,
                                                  f16* __restrict__ vto) {
  __shared__ __align__(16) f16 As[128 * 32];   // 8 KB
  __shared__ __align__(16) f16 Bs[128 * 32];   // 8 KB
  const int z = blockIdx.z;
  const f16* wt = wtb + (size_t)z * HID * HID;
  const float* bias = (z == 0) ? bq : (z == 1 ? bk : bv);
  const int brow = blockIdx.y * 128;
  const int bcol = blockIdx.x * 128;
  const int tid = threadIdx.x, wid = tid >> 6, lane = tid & 63;
  const int wr = wid >> 1, wc = wid & 1;
  const int lrow = lane & 15, lk8 = (lane >> 4) * 8;
  const int srow = lane >> 2;          // staging row within 16-row group
  const int scol = (lane & 3) * 8;     // staging col (f16 elements)

  f32x4 acc[4][4] = {};

  for (int kt = 0; kt < HID; kt += 32) {
    #pragma unroll
    for (int r = 0; r < 2; r++) {
      int row = (wid * 2 + r) * 16 + srow;
      const f16* ga = xb + (size_t)(brow + row) * HID + kt + scol;
      const f16* gb = wt + (size_t)(bcol + row) * HID + kt + scol;
      __builtin_amdgcn_global_load_lds(
          (const __attribute__((address_space(1))) void*)ga,
          (__attribute__((address_space(3))) void*)(As + (wid * 2 + r) * 512),
          16, 0, 0);
      __builtin_amdgcn_global_load_lds(
          (const __attribute__((address_space(1))) void*)gb,
          (__attribute__((address_space(3))) void*)(Bs + (wid * 2 + r) * 512),
          16, 0, 0);
    }
    __syncthreads();

    half8 a[4], b[4];
    #pragma unroll
    for (int m = 0; m < 4; m++)
      a[m] = *(const half8*)&As[(wr * 64 + m * 16 + lrow) * 32 + lk8];
    #pragma unroll
    for (int n = 0; n < 4; n++)
      b[n] = *(const half8*)&Bs[(wc * 64 + n * 16 + lrow) * 32 + lk8];
    #pragma unroll
    for (int m = 0; m < 4; m++)
      #pragma unroll
      for (int n = 0; n < 4; n++)
        acc[m][n] = __builtin_amdgcn_mfma_f32_16x16x32_f16(a[m], b[n], acc[m][n], 0, 0, 0);
    __syncthreads();
  }

  #pragma unroll
  for (int m = 0; m < 4; m++) {
    int row0 = brow + wr * 64 + m * 16 + (lane >> 4) * 4;
    #pragma unroll
    for (int n = 0; n < 4; n++) {
      int col = bcol + wc * 64 + n * 16 + lrow;
      float bsv = bias[col];
      int h = col >> 6, d = col & 63;
      #pragma unroll
      for (int i = 0; i < 4; i++) {
        f16 v = (f16)(acc[m][n][i] + bsv);
        int r2 = row0 + i;
        if (z == 2)      vto[(size_t)(h * HD + d) * S_LEN + r2] = v;
        else if (z == 1) ko[((size_t)h * S_LEN + r2) * HD + d] = v;
        else             qo[((size_t)h * S_LEN + r2) * HD + d] = v;
      }
    }
  }
}

// ---------------- flash attention (swapped-operand, split-KV) ----------------
// grid (64 q-blocks, 12 heads, split). 4 waves/block, wave owns 16 q rows.
// QK^T computed as mfma(K,Q) -> lane holds q=lane&15, k=(lane>>4)*4+i: softmax
// stats are per-lane scalars. PV computed as O^T = mfma(V^T, P): acc q also on
// lane&15 -> no cross-lane redistribution of al/li.
__global__ __launch_bounds__(256, 8) void k_attn(const f16* __restrict__ qb,
                                                 const f16* __restrict__ kb,
                                                 const f16* __restrict__ vt,
                                                 const float* __restrict__ mask,
                                                 float* __restrict__ dsto,   // out (direct) or opart
                                                 float* __restrict__ ml,
                                                 int nkt, int direct) {
  __shared__ __align__(16) f16 P[4][16 * 72];   // per-wave P tile, stride 72
  const int h = blockIdx.y, z = blockIdx.z;
  const int tid = threadIdx.x, wid = tid >> 6, lane = tid & 63;
  const int lrow = lane & 15, lk8 = (lane >> 4) * 8, g4 = (lane >> 4) * 4;
  const int qrow0 = blockIdx.x * 64 + wid * 16;
  const size_t hqk = (size_t)h * (S_LEN * HD);
  const int kt0 = z * nkt * 64;
  f16* Pw = &P[wid][0];

  const half8 aq0 = *(const half8*)&qb[hqk + (size_t)(qrow0 + lrow) * HD + lk8];
  const half8 aq1 = *(const half8*)&qb[hqk + (size_t)(qrow0 + lrow) * HD + 32 + lk8];

  f32x4 acc[4] = {};
  float mi = -INFINITY, li = 0.f;
  const float scale = 0.125f;   // 1/sqrt(64)

  for (int it = 0; it < nkt; ++it) {
    const int kt = kt0 + it * 64;
    // ---- QK^T swapped: sp[nt][i] = S[k = nt*16+g4+i][q = lrow] ----
    f32x4 sp[4];
    #pragma unroll
    for (int nt = 0; nt < 4; nt++) {
      const f16* kp = &kb[hqk + (size_t)(kt + nt * 16 + lrow) * HD + lk8];
      half8 b0 = *(const half8*)kp;
      half8 b1 = *(const half8*)(kp + 32);
      f32x4 sv = {};
      sv = __builtin_amdgcn_mfma_f32_16x16x32_f16(b0, aq0, sv, 0, 0, 0);
      sv = __builtin_amdgcn_mfma_f32_16x16x32_f16(b1, aq1, sv, 0, 0, 0);
      sp[nt] = sv;
    }
    // ---- scale + mask, per-lane local max over 16 k's ----
    float mloc = -INFINITY;
    #pragma unroll
    for (int nt = 0; nt < 4; nt++) {
      float4 mk = *(const float4*)&mask[kt + nt * 16 + g4];
      sp[nt][0] = sp[nt][0] * scale + mk.x;
      sp[nt][1] = sp[nt][1] * scale + mk.y;
      sp[nt][2] = sp[nt][2] * scale + mk.z;
      sp[nt][3] = sp[nt][3] * scale + mk.w;
      mloc = fmaxf(mloc, fmaxf(fmaxf(sp[nt][0], sp[nt][1]), fmaxf(sp[nt][2], sp[nt][3])));
    }
    // ---- cross-group reduce (only 2 shfl rounds; lanes with same lane&15) ----
    mloc = fmaxf(mloc, __shfl_xor(mloc, 16, 64));
    mloc = fmaxf(mloc, __shfl_xor(mloc, 32, 64));
    const float mn = fmaxf(mi, mloc);
    const float al = __expf(mi - mn);
    mi = mn;
    float rs = 0.f;
    #pragma unroll
    for (int nt = 0; nt < 4; nt++)
      #pragma unroll
      for (int i = 0; i < 4; i++) {
        sp[nt][i] = __expf(sp[nt][i] - mn);
        rs += sp[nt][i];
      }
    rs += __shfl_xor(rs, 16, 64);
    rs += __shfl_xor(rs, 32, 64);
    li = li * al + rs;
    #pragma unroll
    for (int nd = 0; nd < 4; nd++) {
      acc[nd][0] *= al; acc[nd][1] *= al; acc[nd][2] *= al; acc[nd][3] *= al;
    }
    // ---- P -> LDS, row-major [q=lrow][k], half4 packed writes ----
    #pragma unroll
    for (int nt = 0; nt < 4; nt++) {
      half4 h4;
      h4[0] = (f16)sp[nt][0]; h4[1] = (f16)sp[nt][1];
      h4[2] = (f16)sp[nt][2]; h4[3] = (f16)sp[nt][3];
      *(half4*)&Pw[lrow * 72 + nt * 16 + g4] = h4;
    }
    // ---- PV swapped: acc = O^T[d][q] += V^T[d][k] * P^T[k][q] ----
    #pragma unroll
    for (int k2 = 0; k2 < 2; k2++) {
      half8 bp = *(const half8*)&Pw[lrow * 72 + k2 * 32 + lk8];
      #pragma unroll
      for (int nd = 0; nd < 4; nd++) {
        const f16* vp = &vt[((size_t)(h * HD + nd * 16 + lrow)) * S_LEN + kt + k2 * 32 + lk8];
        half8 av = *(const half8*)vp;
        acc[nd] = __builtin_amdgcn_mfma_f32_16x16x32_f16(av, bp, acc[nd], 0, 0, 0);
      }
    }
  }

  const float inv = (li > 0.f) ? (1.f / li) : 0.f;
  if (direct) {
    // out[q][h*64+d], d = nd*16 + g4 + i  -> float4 per nd
    #pragma unroll
    for (int nd = 0; nd < 4; nd++) {
      float4 o = make_float4(acc[nd][0] * inv, acc[nd][1] * inv,
                             acc[nd][2] * inv, acc[nd][3] * inv);
      *(float4*)&dsto[(size_t)(qrow0 + lrow) * HID + h * HD + nd * 16 + g4] = o;
    }
  } else {
    const size_t rbase = ((size_t)z * NH + h) * S_LEN + qrow0 + lrow;
    #pragma unroll
    for (int nd = 0; nd < 4; nd++) {
      float4 o = make_float4(acc[nd][0] * inv, acc[nd][1] * inv,
                             acc[nd][2] * inv, acc[nd][3] * inv);
      *(float4*)&dsto[rbase * HD + nd * 16 + g4] = o;
    }
    if (lane < 16) {
      ml[rbase * 2]     = mi;
      ml[rbase * 2 + 1] = li;
    }
  }
}

// ---------------- split-KV combine ----------------
__global__ __launch_bounds__(256) void k_combine(const float* __restrict__ opart,
                                                 const float* __restrict__ ml,
                                                 float* __restrict__ out, int split) {
  const int gid = blockIdx.x * 256 + threadIdx.x;   // NH*S*16 threads
  const int row = gid >> 4;                          // h*S + q
  const int d0 = (gid & 15) << 2;
  const int h = row >> 12, q = row & (S_LEN - 1);
  float M = -INFINITY;
  for (int zz = 0; zz < split; zz++)
    M = fmaxf(M, ml[((size_t)zz * NH * S_LEN + row) * 2]);
  float wsum = 0.f;
  float o0 = 0.f, o1 = 0.f, o2 = 0.f, o3 = 0.f;
  for (int zz = 0; zz < split; zz++) {
    const size_t r = (size_t)zz * NH * S_LEN + row;
    float m = ml[r * 2], l = ml[r * 2 + 1];
    if (l > 0.f) {
      float w = l * __expf(m - M);
      float4 v = *(const float4*)&opart[r * HD + d0];
      wsum += w;
      o0 += w * v.x; o1 += w * v.y; o2 += w * v.z; o3 += w * v.w;
    }
  }
  const float inv = (wsum > 0.f) ? (1.f / wsum) : 0.f;
  *(float4*)&out[(size_t)q * HID + h * HD + d0] =
      make_float4(o0 * inv, o1 * inv, o2 * inv, o3 * inv);
}

extern "C" void kernel_launch(void* const* d_in, const int* in_sizes, int n_in,
                              void* d_out, int out_size, void* d_ws, size_t ws_size,
                              hipStream_t stream) {
  const float* x    = (const float*)d_in[0];
  const float* mask = (const float*)d_in[1];
  const float* Wq   = (const float*)d_in[2];
  const float* bq   = (const float*)d_in[3];
  const float* Wk   = (const float*)d_in[4];
  const float* bk   = (const float*)d_in[5];
  const float* Wv   = (const float*)d_in[6];
  const float* bv   = (const float*)d_in[7];
  float* out = (float*)d_out;

  char* ws = (char*)d_ws;
  f16* xb  = (f16*)(ws);                       // 4096*768*2       = 6291456 B
  f16* wtb = (f16*)(ws + 6291456);             // 3*768*768*2      = 3538944 B
  f16* qbb = (f16*)(ws + 9830400);             // 12*4096*64*2     = 6291456 B
  f16* kbb = (f16*)(ws + 16121856);            // 6291456 B
  f16* vtb = (f16*)(ws + 22413312);            // 6291456 B  (end 28704768)

  const size_t base   = 28704768;
  const size_t o_per  = (size_t)NH * S_LEN * HD * 4;   // 12582912
  const size_t ml_per = (size_t)NH * S_LEN * 2 * 4;    // 393216

  int split = 1;
  if (ws_size >= base + 4 * (o_per + ml_per))      split = 4;
  else if (ws_size >= base + 2 * (o_per + ml_per)) split = 2;

  k_convert_x<<<dim3(3072), dim3(256), 0, stream>>>(x, xb);
  k_transw<<<dim3(24, 24, 3), dim3(32, 8), 0, stream>>>(Wq, Wk, Wv, wtb);
  k_gemm_qkv<<<dim3(6, 32, 3), dim3(256), 0, stream>>>(xb, wtb, bq, bk, bv, qbb, kbb, vtb);

  if (split == 1) {
    k_attn<<<dim3(64, NH, 1), dim3(256), 0, stream>>>(qbb, kbb, vtb, mask, out, out,
                                                      S_LEN / 64, 1);
  } else {
    float* opart = (float*)(ws + base);
    float* ml    = (float*)(ws + base + (size_t)split * o_per);
    k_attn<<<dim3(64, NH, split), dim3(256), 0, stream>>>(qbb, kbb, vtb, mask, opart, ml,
                                                          S_LEN / (64 * split), 0);
    k_combine<<<dim3(NH * S_LEN * 16 / 256), dim3(256), 0, stream>>>(opart, ml, out, split);
  }
}

// Round 4
// 166.800 us; speedup vs baseline: 3.1246x; 3.1246x over previous
//
#include <hip/hip_runtime.h>

typedef _Float16 f16;
typedef __attribute__((ext_vector_type(8))) _Float16 half8;
typedef __attribute__((ext_vector_type(4))) _Float16 half4;
typedef __attribute__((ext_vector_type(4))) float f32x4;

#define S_LEN 4096
#define HID   768
#define NH    12
#define HD    64

#define EXP2(x) __builtin_amdgcn_exp2f(x)

// ---------------- convert hidden_states f32 -> f16 ----------------
__global__ __launch_bounds__(256) void k_convert_x(const float* __restrict__ x,
                                                   f16* __restrict__ xb) {
  int i = blockIdx.x * 256 + threadIdx.x;          // one float4 per thread
  float4 v = ((const float4*)x)[i];
  half4 h;
  h[0] = (f16)v.x; h[1] = (f16)v.y; h[2] = (f16)v.z; h[3] = (f16)v.w;
  *(half4*)&xb[(size_t)i * 4] = h;
}

// ---------------- transpose W [K,N] -> wt [N,K], f32 -> f16 ----------------
__global__ __launch_bounds__(256) void k_transw(const float* __restrict__ Wq,
                                                const float* __restrict__ Wk,
                                                const float* __restrict__ Wv,
                                                f16* __restrict__ wtb) {
  __shared__ float tile[32][33];
  const float* W = (blockIdx.z == 0) ? Wq : (blockIdx.z == 1 ? Wk : Wv);
  f16* wt = wtb + (size_t)blockIdx.z * HID * HID;
  int k0 = blockIdx.y * 32, n0 = blockIdx.x * 32;
  int tx = threadIdx.x, ty = threadIdx.y;
  #pragma unroll
  for (int j = ty; j < 32; j += 8)
    tile[j][tx] = W[(size_t)(k0 + j) * HID + n0 + tx];
  __syncthreads();
  #pragma unroll
  for (int j = ty; j < 32; j += 8)
    wt[(size_t)(n0 + j) * HID + k0 + tx] = (f16)tile[tx][j];
}

// ---------------- QKV projection GEMM (m97-style, 128x128 tile) ----------------
__global__ __launch_bounds__(256) void k_gemm_qkv(const f16* __restrict__ xb,
                                                  const f16* __restrict__ wtb,
                                                  const float* __restrict__ bq,
                                                  const float* __restrict__ bk,
                                                  const float* __restrict__ bv,
                                                  f16* __restrict__ qo,
                                                  f16* __restrict__ ko,
                                                  f16* __restrict__ vto) {
  __shared__ __align__(16) f16 As[128 * 32];   // 8 KB
  __shared__ __align__(16) f16 Bs[128 * 32];   // 8 KB
  const int z = blockIdx.z;
  const f16* wt = wtb + (size_t)z * HID * HID;
  const float* bias = (z == 0) ? bq : (z == 1 ? bk : bv);
  const int brow = blockIdx.y * 128;
  const int bcol = blockIdx.x * 128;
  const int tid = threadIdx.x, wid = tid >> 6, lane = tid & 63;
  const int wr = wid >> 1, wc = wid & 1;
  const int lrow = lane & 15, lk8 = (lane >> 4) * 8;
  const int srow = lane >> 2;          // staging row within 16-row group
  const int scol = (lane & 3) * 8;     // staging col (f16 elements)

  f32x4 acc[4][4] = {};

  for (int kt = 0; kt < HID; kt += 32) {
    #pragma unroll
    for (int r = 0; r < 2; r++) {
      int row = (wid * 2 + r) * 16 + srow;
      const f16* ga = xb + (size_t)(brow + row) * HID + kt + scol;
      const f16* gb = wt + (size_t)(bcol + row) * HID + kt + scol;
      __builtin_amdgcn_global_load_lds(
          (const __attribute__((address_space(1))) void*)ga,
          (__attribute__((address_space(3))) void*)(As + (wid * 2 + r) * 512),
          16, 0, 0);
      __builtin_amdgcn_global_load_lds(
          (const __attribute__((address_space(1))) void*)gb,
          (__attribute__((address_space(3))) void*)(Bs + (wid * 2 + r) * 512),
          16, 0, 0);
    }
    __syncthreads();

    half8 a[4], b[4];
    #pragma unroll
    for (int m = 0; m < 4; m++)
      a[m] = *(const half8*)&As[(wr * 64 + m * 16 + lrow) * 32 + lk8];
    #pragma unroll
    for (int n = 0; n < 4; n++)
      b[n] = *(const half8*)&Bs[(wc * 64 + n * 16 + lrow) * 32 + lk8];
    #pragma unroll
    for (int m = 0; m < 4; m++)
      #pragma unroll
      for (int n = 0; n < 4; n++)
        acc[m][n] = __builtin_amdgcn_mfma_f32_16x16x32_f16(a[m], b[n], acc[m][n], 0, 0, 0);
    __syncthreads();
  }

  #pragma unroll
  for (int m = 0; m < 4; m++) {
    int row0 = brow + wr * 64 + m * 16 + (lane >> 4) * 4;
    #pragma unroll
    for (int n = 0; n < 4; n++) {
      int col = bcol + wc * 64 + n * 16 + lrow;
      float bsv = bias[col];
      int h = col >> 6, d = col & 63;
      #pragma unroll
      for (int i = 0; i < 4; i++) {
        f16 v = (f16)(acc[m][n][i] + bsv);
        int r2 = row0 + i;
        if (z == 2)      vto[(size_t)(h * HD + d) * S_LEN + r2] = v;
        else if (z == 1) ko[((size_t)h * S_LEN + r2) * HD + d] = v;
        else             qo[((size_t)h * S_LEN + r2) * HD + d] = v;
      }
    }
  }
}

// ---------------- flash attention (swapped-operand, LDS-staged K/V, 2-phase) ----
// grid (64 q-blocks, 12 heads), 4 waves/block. Block stages K[64][64] and
// V^T[64][64] tiles to LDS (double-buffered, global_load_lds w=16, XOR-swizzled
// via pre-swizzled global source; LDS dest linear per m104). Swapped QK^T:
// lane holds q=lane&15 -> per-lane softmax stats, 2 shfl rounds only.
__global__ __launch_bounds__(256) void k_attn(const f16* __restrict__ qb,
                                              const f16* __restrict__ kb,
                                              const f16* __restrict__ vt,
                                              const float* __restrict__ mask,
                                              float* __restrict__ out) {
  __shared__ __align__(16) f16 Ks[2][64 * 64];   // 8 KB each buf
  __shared__ __align__(16) f16 Vs[2][64 * 64];
  __shared__ __align__(16) f16 P[4][16 * 72];    // per-wave P tile, stride 72
  const int h = blockIdx.y;
  const int tid = threadIdx.x, wid = tid >> 6, lane = tid & 63;
  const int lrow = lane & 15, lk8 = (lane >> 4) * 8, g4 = (lane >> 4) * 4;
  const int grp = lane >> 4;                 // 0..3
  const int qrow0 = blockIdx.x * 64 + wid * 16;
  const size_t hqk = (size_t)h * (S_LEN * HD);
  f16* Pw = &P[wid][0];
  const float LOG2E = 1.4426950408889634f;
  const float scale2 = 0.125f * LOG2E;       // (1/sqrt(64)) * log2(e)

  // staging geometry: 2 rounds x 256 threads x 16B per matrix (8 KB tile)
  const int srow = tid >> 3;                 // 0..31 (+32*r)
  const int sc   = tid & 7;                  // dest chunk within row

  const half8 aq0 = *(const half8*)&qb[hqk + (size_t)(qrow0 + lrow) * HD + lk8];
  const half8 aq1 = *(const half8*)&qb[hqk + (size_t)(qrow0 + lrow) * HD + 32 + lk8];

  f32x4 acc[4] = {};
  float mi = -INFINITY, li = 0.f;

  auto stage = [&](int buf, int kt) {
    #pragma unroll
    for (int r = 0; r < 2; r++) {
      const int row = r * 32 + srow;
      const int scol = ((sc ^ (row & 7)) << 3);              // swizzled source chunk
      const f16* gk = kb + hqk + (size_t)(kt + row) * HD + scol;
      const f16* gv = vt + ((size_t)(h * HD + row)) * S_LEN + kt + scol;
      f16* dk = &Ks[buf][r * 2048 + (tid << 3)];             // linear dest = base+lane*16B
      f16* dv = &Vs[buf][r * 2048 + (tid << 3)];
      __builtin_amdgcn_global_load_lds(
          (const __attribute__((address_space(1))) void*)gk,
          (__attribute__((address_space(3))) void*)dk, 16, 0, 0);
      __builtin_amdgcn_global_load_lds(
          (const __attribute__((address_space(1))) void*)gv,
          (__attribute__((address_space(3))) void*)dv, 16, 0, 0);
    }
  };

  stage(0, 0);
  __syncthreads();

  for (int it = 0; it < S_LEN / 64; ++it) {
    const int cur = it & 1;
    const int kt = it * 64;
    if (it + 1 < S_LEN / 64) stage(cur ^ 1, kt + 64);   // async prefetch next tile

    // ---- QK^T swapped from LDS: sp[nt][i] = S[k=nt*16+g4+i][q=lrow] ----
    f32x4 sp[4];
    #pragma unroll
    for (int nt = 0; nt < 4; nt++) {
      const int row = nt * 16 + lrow;
      const int x0 = ((grp ^ (row & 7)) << 3);
      const int x1 = (((4 + grp) ^ (row & 7)) << 3);
      half8 b0 = *(const half8*)&Ks[cur][row * 64 + x0];
      half8 b1 = *(const half8*)&Ks[cur][row * 64 + x1];
      f32x4 sv = {};
      sv = __builtin_amdgcn_mfma_f32_16x16x32_f16(b0, aq0, sv, 0, 0, 0);
      sv = __builtin_amdgcn_mfma_f32_16x16x32_f16(b1, aq1, sv, 0, 0, 0);
      sp[nt] = sv;
    }
    // ---- scale+mask in log2 domain, per-lane max over 16 k's ----
    float mloc = -INFINITY;
    #pragma unroll
    for (int nt = 0; nt < 4; nt++) {
      float4 mk = *(const float4*)&mask[kt + nt * 16 + g4];
      sp[nt][0] = sp[nt][0] * scale2 + mk.x * LOG2E;
      sp[nt][1] = sp[nt][1] * scale2 + mk.y * LOG2E;
      sp[nt][2] = sp[nt][2] * scale2 + mk.z * LOG2E;
      sp[nt][3] = sp[nt][3] * scale2 + mk.w * LOG2E;
      mloc = fmaxf(mloc, fmaxf(fmaxf(sp[nt][0], sp[nt][1]), fmaxf(sp[nt][2], sp[nt][3])));
    }
    mloc = fmaxf(mloc, __shfl_xor(mloc, 16, 64));
    mloc = fmaxf(mloc, __shfl_xor(mloc, 32, 64));
    const float mn = fmaxf(mi, mloc);
    const float al = EXP2(mi - mn);
    mi = mn;
    float rs = 0.f;
    #pragma unroll
    for (int nt = 0; nt < 4; nt++)
      #pragma unroll
      for (int i = 0; i < 4; i++) {
        sp[nt][i] = EXP2(sp[nt][i] - mn);
        rs += sp[nt][i];
      }
    rs += __shfl_xor(rs, 16, 64);
    rs += __shfl_xor(rs, 32, 64);
    li = li * al + rs;
    #pragma unroll
    for (int nd = 0; nd < 4; nd++) {
      acc[nd][0] *= al; acc[nd][1] *= al; acc[nd][2] *= al; acc[nd][3] *= al;
    }
    // ---- P -> LDS row-major [q=lrow][k], half4 packed (per-wave, no barrier) ----
    #pragma unroll
    for (int nt = 0; nt < 4; nt++) {
      half4 h4;
      h4[0] = (f16)sp[nt][0]; h4[1] = (f16)sp[nt][1];
      h4[2] = (f16)sp[nt][2]; h4[3] = (f16)sp[nt][3];
      *(half4*)&Pw[lrow * 72 + nt * 16 + g4] = h4;
    }
    // ---- PV swapped from LDS: acc[nd] = O^T[d][q] += V^T[d][k] P^T[k][q] ----
    #pragma unroll
    for (int k2 = 0; k2 < 2; k2++) {
      half8 bp = *(const half8*)&Pw[lrow * 72 + k2 * 32 + lk8];
      #pragma unroll
      for (int nd = 0; nd < 4; nd++) {
        const int vr = nd * 16 + lrow;
        const int xc = (((k2 * 4 + grp) ^ (vr & 7)) << 3);
        half8 av = *(const half8*)&Vs[cur][vr * 64 + xc];
        acc[nd] = __builtin_amdgcn_mfma_f32_16x16x32_f16(av, bp, acc[nd], 0, 0, 0);
      }
    }
    __syncthreads();   // drain prefetch (next buf ready), release cur buf
  }

  const float inv = (li > 0.f) ? (1.f / li) : 0.f;
  #pragma unroll
  for (int nd = 0; nd < 4; nd++) {
    float4 o = make_float4(acc[nd][0] * inv, acc[nd][1] * inv,
                           acc[nd][2] * inv, acc[nd][3] * inv);
    *(float4*)&out[(size_t)(qrow0 + lrow) * HID + h * HD + nd * 16 + g4] = o;
  }
}

extern "C" void kernel_launch(void* const* d_in, const int* in_sizes, int n_in,
                              void* d_out, int out_size, void* d_ws, size_t ws_size,
                              hipStream_t stream) {
  const float* x    = (const float*)d_in[0];
  const float* mask = (const float*)d_in[1];
  const float* Wq   = (const float*)d_in[2];
  const float* bq   = (const float*)d_in[3];
  const float* Wk   = (const float*)d_in[4];
  const float* bk   = (const float*)d_in[5];
  const float* Wv   = (const float*)d_in[6];
  const float* bv   = (const float*)d_in[7];
  float* out = (float*)d_out;

  char* ws = (char*)d_ws;
  f16* xb  = (f16*)(ws);                       // 4096*768*2       = 6291456 B
  f16* wtb = (f16*)(ws + 6291456);             // 3*768*768*2      = 3538944 B
  f16* qbb = (f16*)(ws + 9830400);             // 12*4096*64*2     = 6291456 B
  f16* kbb = (f16*)(ws + 16121856);            // 6291456 B
  f16* vtb = (f16*)(ws + 22413312);            // 6291456 B  (end 28704768)

  k_convert_x<<<dim3(3072), dim3(256), 0, stream>>>(x, xb);
  k_transw<<<dim3(24, 24, 3), dim3(32, 8), 0, stream>>>(Wq, Wk, Wv, wtb);
  k_gemm_qkv<<<dim3(6, 32, 3), dim3(256), 0, stream>>>(xb, wtb, bq, bk, bv, qbb, kbb, vtb);
  k_attn<<<dim3(64, NH), dim3(256), 0, stream>>>(qbb, kbb, vtb, mask, out);
}

// Round 6
// 149.174 us; speedup vs baseline: 3.4938x; 1.1182x over previous
//
#include <hip/hip_runtime.h>

typedef _Float16 f16;
typedef __attribute__((ext_vector_type(8))) _Float16 half8;
typedef __attribute__((ext_vector_type(4))) _Float16 half4;
typedef __attribute__((ext_vector_type(2))) _Float16 half2v;
typedef __attribute__((ext_vector_type(4))) float f32x4;

#define S_LEN 4096
#define HID   768
#define NH    12
#define HD    64

#define EXP2(x) __builtin_amdgcn_exp2f(x)
#define PKRTZ(a, b) __builtin_bit_cast(half2v, __builtin_amdgcn_cvt_pkrtz((a), (b)))

// ---------------- convert hidden_states f32 -> f16 ----------------
__global__ __launch_bounds__(256) void k_convert_x(const float* __restrict__ x,
                                                   f16* __restrict__ xb) {
  int i = blockIdx.x * 256 + threadIdx.x;          // one float4 per thread
  float4 v = ((const float4*)x)[i];
  half4 h;
  h[0] = (f16)v.x; h[1] = (f16)v.y; h[2] = (f16)v.z; h[3] = (f16)v.w;
  *(half4*)&xb[(size_t)i * 4] = h;
}

// ---------------- mask * log2(e) precompute (into dead xb space) ----------------
__global__ __launch_bounds__(256) void k_maskcvt(const float* __restrict__ m,
                                                 float* __restrict__ m2) {
  int i = blockIdx.x * 256 + threadIdx.x;          // one float4 per thread
  const float LOG2E = 1.4426950408889634f;
  float4 v = ((const float4*)m)[i];
  ((float4*)m2)[i] = make_float4(v.x * LOG2E, v.y * LOG2E, v.z * LOG2E, v.w * LOG2E);
}

// ---------------- transpose W [K,N] -> wt [N,K], f32 -> f16 ----------------
__global__ __launch_bounds__(256) void k_transw(const float* __restrict__ Wq,
                                                const float* __restrict__ Wk,
                                                const float* __restrict__ Wv,
                                                f16* __restrict__ wtb) {
  __shared__ float tile[32][33];
  const float* W = (blockIdx.z == 0) ? Wq : (blockIdx.z == 1 ? Wk : Wv);
  f16* wt = wtb + (size_t)blockIdx.z * HID * HID;
  int k0 = blockIdx.y * 32, n0 = blockIdx.x * 32;
  int tx = threadIdx.x, ty = threadIdx.y;
  #pragma unroll
  for (int j = ty; j < 32; j += 8)
    tile[j][tx] = W[(size_t)(k0 + j) * HID + n0 + tx];
  __syncthreads();
  #pragma unroll
  for (int j = ty; j < 32; j += 8)
    wt[(size_t)(n0 + j) * HID + k0 + tx] = (f16)tile[tx][j];
}

// ---------------- QKV projection GEMM (m97-style, 128x128 tile) ----------------
__global__ __launch_bounds__(256) void k_gemm_qkv(const f16* __restrict__ xb,
                                                  const f16* __restrict__ wtb,
                                                  const float* __restrict__ bq,
                                                  const float* __restrict__ bk,
                                                  const float* __restrict__ bv,
                                                  f16* __restrict__ qo,
                                                  f16* __restrict__ ko,
                                                  f16* __restrict__ vto) {
  __shared__ __align__(16) f16 As[128 * 32];   // 8 KB
  __shared__ __align__(16) f16 Bs[128 * 32];   // 8 KB
  const int z = blockIdx.z;
  const f16* wt = wtb + (size_t)z * HID * HID;
  const float* bias = (z == 0) ? bq : (z == 1 ? bk : bv);
  const int brow = blockIdx.y * 128;
  const int bcol = blockIdx.x * 128;
  const int tid = threadIdx.x, wid = tid >> 6, lane = tid & 63;
  const int wr = wid >> 1, wc = wid & 1;
  const int lrow = lane & 15, lk8 = (lane >> 4) * 8;
  const int srow = lane >> 2;          // staging row within 16-row group
  const int scol = (lane & 3) * 8;     // staging col (f16 elements)

  f32x4 acc[4][4] = {};

  for (int kt = 0; kt < HID; kt += 32) {
    #pragma unroll
    for (int r = 0; r < 2; r++) {
      int row = (wid * 2 + r) * 16 + srow;
      const f16* ga = xb + (size_t)(brow + row) * HID + kt + scol;
      const f16* gb = wt + (size_t)(bcol + row) * HID + kt + scol;
      __builtin_amdgcn_global_load_lds(
          (const __attribute__((address_space(1))) void*)ga,
          (__attribute__((address_space(3))) void*)(As + (wid * 2 + r) * 512),
          16, 0, 0);
      __builtin_amdgcn_global_load_lds(
          (const __attribute__((address_space(1))) void*)gb,
          (__attribute__((address_space(3))) void*)(Bs + (wid * 2 + r) * 512),
          16, 0, 0);
    }
    __syncthreads();

    half8 a[4], b[4];
    #pragma unroll
    for (int m = 0; m < 4; m++)
      a[m] = *(const half8*)&As[(wr * 64 + m * 16 + lrow) * 32 + lk8];
    #pragma unroll
    for (int n = 0; n < 4; n++)
      b[n] = *(const half8*)&Bs[(wc * 64 + n * 16 + lrow) * 32 + lk8];
    #pragma unroll
    for (int m = 0; m < 4; m++)
      #pragma unroll
      for (int n = 0; n < 4; n++)
        acc[m][n] = __builtin_amdgcn_mfma_f32_16x16x32_f16(a[m], b[n], acc[m][n], 0, 0, 0);
    __syncthreads();
  }

  #pragma unroll
  for (int m = 0; m < 4; m++) {
    int row0 = brow + wr * 64 + m * 16 + (lane >> 4) * 4;
    #pragma unroll
    for (int n = 0; n < 4; n++) {
      int col = bcol + wc * 64 + n * 16 + lrow;
      float bsv = bias[col];
      int h = col >> 6, d = col & 63;
      #pragma unroll
      for (int i = 0; i < 4; i++) {
        f16 v = (f16)(acc[m][n][i] + bsv);
        int r2 = row0 + i;
        if (z == 2)      vto[(size_t)(h * HD + d) * S_LEN + r2] = v;
        else if (z == 1) ko[((size_t)h * S_LEN + r2) * HD + d] = v;
        else             qo[((size_t)h * S_LEN + r2) * HD + d] = v;
      }
    }
  }
}

// ---------------- flash attention (swapped-operand, LDS-staged K/V, 2-phase) ----
// mask2 is mask*log2e (precomputed). Softmax in log2 domain with defer-max
// (T13, THR=8 -> P <= 256, f16-safe). setprio around MFMA clusters (T5).
__global__ __launch_bounds__(256) void k_attn(const f16* __restrict__ qb,
                                              const f16* __restrict__ kb,
                                              const f16* __restrict__ vt,
                                              const float* __restrict__ mask2,
                                              float* __restrict__ out) {
  __shared__ __align__(16) f16 Ks[2][64 * 64];   // 8 KB each buf
  __shared__ __align__(16) f16 Vs[2][64 * 64];
  __shared__ __align__(16) f16 P[4][16 * 72];    // per-wave P tile, stride 72
  const int h = blockIdx.y;
  const int tid = threadIdx.x, wid = tid >> 6, lane = tid & 63;
  const int lrow = lane & 15, lk8 = (lane >> 4) * 8, g4 = (lane >> 4) * 4;
  const int grp = lane >> 4;                 // 0..3
  const int qrow0 = blockIdx.x * 64 + wid * 16;
  const size_t hqk = (size_t)h * (S_LEN * HD);
  f16* Pw = &P[wid][0];
  const float LOG2E = 1.4426950408889634f;
  const float scale2 = 0.125f * LOG2E;       // (1/sqrt(64)) * log2(e)

  // staging geometry: 2 rounds x 256 threads x 16B per matrix (8 KB tile)
  const int srow = tid >> 3;                 // 0..31 (+32*r)
  const int sc   = tid & 7;                  // dest chunk within row

  const half8 aq0 = *(const half8*)&qb[hqk + (size_t)(qrow0 + lrow) * HD + lk8];
  const half8 aq1 = *(const half8*)&qb[hqk + (size_t)(qrow0 + lrow) * HD + 32 + lk8];

  f32x4 acc[4] = {};
  float mi = -INFINITY, li = 0.f;

  auto stage = [&](int buf, int kt) {
    #pragma unroll
    for (int r = 0; r < 2; r++) {
      const int row = r * 32 + srow;
      const int scol = ((sc ^ (row & 7)) << 3);              // swizzled source chunk
      const f16* gk = kb + hqk + (size_t)(kt + row) * HD + scol;
      const f16* gv = vt + ((size_t)(h * HD + row)) * S_LEN + kt + scol;
      f16* dk = &Ks[buf][r * 2048 + (tid << 3)];             // linear dest = base+lane*16B
      f16* dv = &Vs[buf][r * 2048 + (tid << 3)];
      __builtin_amdgcn_global_load_lds(
          (const __attribute__((address_space(1))) void*)gk,
          (__attribute__((address_space(3))) void*)dk, 16, 0, 0);
      __builtin_amdgcn_global_load_lds(
          (const __attribute__((address_space(1))) void*)gv,
          (__attribute__((address_space(3))) void*)dv, 16, 0, 0);
    }
  };

  stage(0, 0);
  __syncthreads();

  for (int it = 0; it < S_LEN / 64; ++it) {
    const int cur = it & 1;
    const int kt = it * 64;
    if (it + 1 < S_LEN / 64) stage(cur ^ 1, kt + 64);   // async prefetch next tile

    // ---- QK^T swapped from LDS: sp[nt][i] = S[k=nt*16+g4+i][q=lrow] ----
    f32x4 sp[4];
    {
      half8 b0[4], b1[4];
      #pragma unroll
      for (int nt = 0; nt < 4; nt++) {
        const int row = nt * 16 + lrow;
        b0[nt] = *(const half8*)&Ks[cur][row * 64 + ((grp ^ (row & 7)) << 3)];
        b1[nt] = *(const half8*)&Ks[cur][row * 64 + (((4 + grp) ^ (row & 7)) << 3)];
      }
      __builtin_amdgcn_s_setprio(1);
      #pragma unroll
      for (int nt = 0; nt < 4; nt++) {
        f32x4 sv = {};
        sv = __builtin_amdgcn_mfma_f32_16x16x32_f16(b0[nt], aq0, sv, 0, 0, 0);
        sv = __builtin_amdgcn_mfma_f32_16x16x32_f16(b1[nt], aq1, sv, 0, 0, 0);
        sp[nt] = sv;
      }
      __builtin_amdgcn_s_setprio(0);
    }
    // ---- scale + pre-scaled mask (log2 domain): 1 fma per score ----
    #pragma unroll
    for (int nt = 0; nt < 4; nt++) {
      float4 mk = *(const float4*)&mask2[kt + nt * 16 + g4];
      sp[nt][0] = sp[nt][0] * scale2 + mk.x;
      sp[nt][1] = sp[nt][1] * scale2 + mk.y;
      sp[nt][2] = sp[nt][2] * scale2 + mk.z;
      sp[nt][3] = sp[nt][3] * scale2 + mk.w;
    }
    // linear fmax chain -> v_max3 fusion
    float mloc = fmaxf(sp[0][0], sp[0][1]);
    mloc = fmaxf(fmaxf(mloc, sp[0][2]), sp[0][3]);
    mloc = fmaxf(fmaxf(mloc, sp[1][0]), sp[1][1]);
    mloc = fmaxf(fmaxf(mloc, sp[1][2]), sp[1][3]);
    mloc = fmaxf(fmaxf(mloc, sp[2][0]), sp[2][1]);
    mloc = fmaxf(fmaxf(mloc, sp[2][2]), sp[2][3]);
    mloc = fmaxf(fmaxf(mloc, sp[3][0]), sp[3][1]);
    mloc = fmaxf(fmaxf(mloc, sp[3][2]), sp[3][3]);
    mloc = fmaxf(mloc, __shfl_xor(mloc, 16, 64));
    mloc = fmaxf(mloc, __shfl_xor(mloc, 32, 64));

    // ---- defer-max (T13): skip rescale when max grew < 8 (log2 units) ----
    float al = 1.f;
    if (!__all(mloc <= mi + 8.f)) {
      const float mn = fmaxf(mi, mloc);
      al = EXP2(mi - mn);
      mi = mn;
      #pragma unroll
      for (int nd = 0; nd < 4; nd++) {
        acc[nd][0] *= al; acc[nd][1] *= al; acc[nd][2] *= al; acc[nd][3] *= al;
      }
    }
    float rs = 0.f;
    #pragma unroll
    for (int nt = 0; nt < 4; nt++)
      #pragma unroll
      for (int i = 0; i < 4; i++) {
        sp[nt][i] = EXP2(sp[nt][i] - mi);
        rs += sp[nt][i];
      }
    rs += __shfl_xor(rs, 16, 64);
    rs += __shfl_xor(rs, 32, 64);
    li = li * al + rs;

    // ---- P -> LDS row-major [q=lrow][k], packed cvt (pkrtz) ----
    #pragma unroll
    for (int nt = 0; nt < 4; nt++) {
      half2v lo = PKRTZ(sp[nt][0], sp[nt][1]);
      half2v hi = PKRTZ(sp[nt][2], sp[nt][3]);
      half4 h4;
      h4[0] = lo[0]; h4[1] = lo[1]; h4[2] = hi[0]; h4[3] = hi[1];
      *(half4*)&Pw[lrow * 72 + nt * 16 + g4] = h4;
    }
    // ---- PV swapped from LDS: acc[nd] = O^T[d][q] += V^T[d][k] P^T[k][q] ----
    #pragma unroll
    for (int k2 = 0; k2 < 2; k2++) {
      half8 bp = *(const half8*)&Pw[lrow * 72 + k2 * 32 + lk8];
      __builtin_amdgcn_s_setprio(1);
      #pragma unroll
      for (int nd = 0; nd < 4; nd++) {
        const int vr = nd * 16 + lrow;
        const int xc = (((k2 * 4 + grp) ^ (vr & 7)) << 3);
        half8 av = *(const half8*)&Vs[cur][vr * 64 + xc];
        acc[nd] = __builtin_amdgcn_mfma_f32_16x16x32_f16(av, bp, acc[nd], 0, 0, 0);
      }
      __builtin_amdgcn_s_setprio(0);
    }
    __syncthreads();   // drain prefetch (next buf ready), release cur buf
  }

  const float inv = (li > 0.f) ? (1.f / li) : 0.f;
  #pragma unroll
  for (int nd = 0; nd < 4; nd++) {
    float4 o = make_float4(acc[nd][0] * inv, acc[nd][1] * inv,
                           acc[nd][2] * inv, acc[nd][3] * inv);
    *(float4*)&out[(size_t)(qrow0 + lrow) * HID + h * HD + nd * 16 + g4] = o;
  }
}

extern "C" void kernel_launch(void* const* d_in, const int* in_sizes, int n_in,
                              void* d_out, int out_size, void* d_ws, size_t ws_size,
                              hipStream_t stream) {
  const float* x    = (const float*)d_in[0];
  const float* mask = (const float*)d_in[1];
  const float* Wq   = (const float*)d_in[2];
  const float* bq   = (const float*)d_in[3];
  const float* Wk   = (const float*)d_in[4];
  const float* bk   = (const float*)d_in[5];
  const float* Wv   = (const float*)d_in[6];
  const float* bv   = (const float*)d_in[7];
  float* out = (float*)d_out;

  char* ws = (char*)d_ws;
  f16* xb  = (f16*)(ws);                       // 4096*768*2       = 6291456 B
  f16* wtb = (f16*)(ws + 6291456);             // 3*768*768*2      = 3538944 B
  f16* qbb = (f16*)(ws + 9830400);             // 12*4096*64*2     = 6291456 B
  f16* kbb = (f16*)(ws + 16121856);            // 6291456 B
  f16* vtb = (f16*)(ws + 22413312);            // 6291456 B  (end 28704768)
  float* mask2 = (float*)ws;                   // reuses xb space AFTER gemm is done

  k_convert_x<<<dim3(3072), dim3(256), 0, stream>>>(x, xb);
  k_transw<<<dim3(24, 24, 3), dim3(32, 8), 0, stream>>>(Wq, Wk, Wv, wtb);
  k_gemm_qkv<<<dim3(6, 32, 3), dim3(256), 0, stream>>>(xb, wtb, bq, bk, bv, qbb, kbb, vtb);
  k_maskcvt<<<dim3(4), dim3(256), 0, stream>>>(mask, mask2);   // xb dead after gemm
  k_attn<<<dim3(64, NH), dim3(256), 0, stream>>>(qbb, kbb, vtb, mask2, out);
}